// Round 1
// baseline (9000.731 us; speedup 1.0000x reference)
//
#include <hip/hip_runtime.h>

// GraphSAGE 3-layer: N=100000 nodes, E=1.6M edges, dims 256->256->128->1.
// Strategy: transform-then-aggregate (linearity of segment-mean), fold 1/deg
// into scatter weight, fuse +b and x@W_r as the accumulator init, fuse relu
// into the next GEMM's X-read.

__global__ __launch_bounds__(256) void count_deg(const int* __restrict__ dst,
                                                 float* __restrict__ deg, int E) {
    int e = blockIdx.x * blockDim.x + threadIdx.x;
    if (e < E) atomicAdd(&deg[dst[e]], 1.0f);
}

__global__ __launch_bounds__(256) void make_inv(float* __restrict__ deg, int n) {
    int i = blockIdx.x * blockDim.x + threadIdx.x;
    if (i < n) deg[i] = 1.0f / fmaxf(deg[i], 1.0f);
}

// Y[M,H] = (relu?)(X[M,K]) @ W[K,H] (+ bias). BM=BH=64, BK=16, 256 thr, 4x4/thread.
template<bool RELU_X, bool BIAS>
__global__ __launch_bounds__(256) void gemm_tiled(
    const float* __restrict__ X, const float* __restrict__ W,
    const float* __restrict__ bias, float* __restrict__ Y,
    int M, int K, int H)
{
    __shared__ float Xs[16][64];   // [k][m]
    __shared__ float Ws[16][64];   // [k][h]
    const int tid = threadIdx.x;
    const int m0 = blockIdx.x * 64;
    const int h0 = blockIdx.y * 64;
    const int r = tid & 15;        // row group (4 rows)
    const int c = tid >> 4;        // col group (4 cols)
    const int lm  = tid >> 2;      // 0..63: X tile row to load
    const int lk4 = (tid & 3) << 2;
    const int lkw = tid >> 4;      // 0..15: W tile row to load
    const int lh4 = (tid & 15) << 2;

    float acc[4][4] = {{0.f, 0.f, 0.f, 0.f}, {0.f, 0.f, 0.f, 0.f},
                       {0.f, 0.f, 0.f, 0.f}, {0.f, 0.f, 0.f, 0.f}};

    for (int k0 = 0; k0 < K; k0 += 16) {
        float4 xv = make_float4(0.f, 0.f, 0.f, 0.f);
        const int gm = m0 + lm;
        if (gm < M) xv = *(const float4*)(X + (size_t)gm * K + k0 + lk4);
        if (RELU_X) {
            xv.x = fmaxf(xv.x, 0.f); xv.y = fmaxf(xv.y, 0.f);
            xv.z = fmaxf(xv.z, 0.f); xv.w = fmaxf(xv.w, 0.f);
        }
        Xs[lk4 + 0][lm] = xv.x;
        Xs[lk4 + 1][lm] = xv.y;
        Xs[lk4 + 2][lm] = xv.z;
        Xs[lk4 + 3][lm] = xv.w;
        *(float4*)(&Ws[lkw][lh4]) =
            *(const float4*)(W + (size_t)(k0 + lkw) * H + h0 + lh4);
        __syncthreads();
        #pragma unroll
        for (int k = 0; k < 16; ++k) {
            const float4 a = *(const float4*)(&Xs[k][r << 2]);
            const float4 b = *(const float4*)(&Ws[k][c << 2]);
            acc[0][0] += a.x * b.x; acc[0][1] += a.x * b.y;
            acc[0][2] += a.x * b.z; acc[0][3] += a.x * b.w;
            acc[1][0] += a.y * b.x; acc[1][1] += a.y * b.y;
            acc[1][2] += a.y * b.z; acc[1][3] += a.y * b.w;
            acc[2][0] += a.z * b.x; acc[2][1] += a.z * b.y;
            acc[2][2] += a.z * b.z; acc[2][3] += a.z * b.w;
            acc[3][0] += a.w * b.x; acc[3][1] += a.w * b.y;
            acc[3][2] += a.w * b.z; acc[3][3] += a.w * b.w;
        }
        __syncthreads();
    }

    float4 bv = make_float4(0.f, 0.f, 0.f, 0.f);
    if (BIAS) bv = *(const float4*)(bias + h0 + (c << 2));
    #pragma unroll
    for (int i = 0; i < 4; ++i) {
        const int gm = m0 + (r << 2) + i;
        if (gm >= M) continue;
        float4 o = make_float4(acc[i][0] + bv.x, acc[i][1] + bv.y,
                               acc[i][2] + bv.z, acc[i][3] + bv.w);
        *(float4*)(Y + (size_t)gm * H + h0 + (c << 2)) = o;
    }
}

// A[dst] += T[src] * inv[dst], feature dim 256: one wave (64 lanes x float4) per edge
__global__ __launch_bounds__(256) void scatter256(
    const int* __restrict__ src, const int* __restrict__ dst,
    const float* __restrict__ inv, const float* __restrict__ T,
    float* __restrict__ A, int E)
{
    const int wave = (int)((blockIdx.x * 256 + threadIdx.x) >> 6);
    const int lane = threadIdx.x & 63;
    if (wave >= E) return;
    const int s = src[wave];
    const int d = dst[wave];
    const float w = inv[d];
    const float4 v = *(const float4*)(T + (size_t)s * 256 + (lane << 2));
    float* o = A + (size_t)d * 256 + (lane << 2);
    atomicAdd(o + 0, v.x * w);
    atomicAdd(o + 1, v.y * w);
    atomicAdd(o + 2, v.z * w);
    atomicAdd(o + 3, v.w * w);
}

// feature dim 128: one half-wave (32 lanes x float4) per edge
__global__ __launch_bounds__(256) void scatter128(
    const int* __restrict__ src, const int* __restrict__ dst,
    const float* __restrict__ inv, const float* __restrict__ T,
    float* __restrict__ A, int E)
{
    const int hw = (int)((blockIdx.x * 256 + threadIdx.x) >> 5);
    const int lane = threadIdx.x & 31;
    if (hw >= E) return;
    const int s = src[hw];
    const int d = dst[hw];
    const float w = inv[d];
    const float4 v = *(const float4*)(T + (size_t)s * 128 + (lane << 2));
    float* o = A + (size_t)d * 128 + (lane << 2);
    atomicAdd(o + 0, v.x * w);
    atomicAdd(o + 1, v.y * w);
    atomicAdd(o + 2, v.z * w);
    atomicAdd(o + 3, v.w * w);
}

// Layer 3: t3 = relu(A2)@Wl3 ; out = relu(A2)@Wr3 + b. One wave per node, K=128.
__global__ __launch_bounds__(256) void gemv_l3(
    const float* __restrict__ A2, const float* __restrict__ Wl,
    const float* __restrict__ Wr, const float* __restrict__ b,
    float* __restrict__ t3, float* __restrict__ out, int M)
{
    const int node = (int)((blockIdx.x * 256 + threadIdx.x) >> 6);
    const int lane = threadIdx.x & 63;
    if (node >= M) return;
    const float* row = A2 + (size_t)node * 128;
    const float a0 = fmaxf(row[lane], 0.f);
    const float a1 = fmaxf(row[64 + lane], 0.f);
    float dl = a0 * Wl[lane] + a1 * Wl[64 + lane];
    float dr = a0 * Wr[lane] + a1 * Wr[64 + lane];
    #pragma unroll
    for (int off = 32; off > 0; off >>= 1) {
        dl += __shfl_down(dl, off, 64);
        dr += __shfl_down(dr, off, 64);
    }
    if (lane == 0) {
        t3[node] = dl;
        out[node] = dr + b[0];
    }
}

__global__ __launch_bounds__(256) void scatter1(
    const int* __restrict__ src, const int* __restrict__ dst,
    const float* __restrict__ inv, const float* __restrict__ t3,
    float* __restrict__ out, int E)
{
    int e = blockIdx.x * blockDim.x + threadIdx.x;
    if (e < E) atomicAdd(&out[dst[e]], t3[src[e]] * inv[dst[e]]);
}

extern "C" void kernel_launch(void* const* d_in, const int* in_sizes, int n_in,
                              void* d_out, int out_size, void* d_ws, size_t ws_size,
                              hipStream_t stream) {
    const float* x   = (const float*)d_in[0];
    const int*   ei  = (const int*)d_in[1];
    const float* Wl1 = (const float*)d_in[2];
    const float* bl1 = (const float*)d_in[3];
    const float* Wr1 = (const float*)d_in[4];
    const float* Wl2 = (const float*)d_in[5];
    const float* bl2 = (const float*)d_in[6];
    const float* Wr2 = (const float*)d_in[7];
    const float* Wl3 = (const float*)d_in[8];
    const float* bl3 = (const float*)d_in[9];
    const float* Wr3 = (const float*)d_in[10];
    float* out = (float*)d_out;

    const int N = in_sizes[0] / 256;     // 100000
    const int E = in_sizes[1] / 2;       // 1600000
    const int* src = ei;
    const int* dst = ei + E;

    // workspace layout (floats)
    float* ws  = (float*)d_ws;
    float* inv = ws;                               // N (reserve 131072)
    float* A1  = ws + 131072;                      // N*256
    float* T1  = A1 + (size_t)N * 256;             // N*256 (reused by T2/A2)
    float* T2  = T1;                               // N*128
    float* A2  = T1 + (size_t)N * 128;             // N*128
    float* t3  = T1 + (size_t)N * 256;             // N
    // total ~205.8 MB

    hipMemsetAsync(inv, 0, (size_t)N * sizeof(float), stream);
    count_deg<<<(E + 255) / 256, 256, 0, stream>>>(dst, inv, E);
    make_inv<<<(N + 255) / 256, 256, 0, stream>>>(inv, N);

    const int mb = (N + 63) / 64;  // 1563

    // Layer 1: T1 = x@Wl1 ; A1 = x@Wr1 + bl1 ; A1[dst] += T1[src]*inv[dst]
    gemm_tiled<false, false><<<dim3(mb, 4), 256, 0, stream>>>(x, Wl1, nullptr, T1, N, 256, 256);
    gemm_tiled<false, true ><<<dim3(mb, 4), 256, 0, stream>>>(x, Wr1, bl1,     A1, N, 256, 256);
    scatter256<<<(E * 64 + 255) / 256, 256, 0, stream>>>(src, dst, inv, T1, A1, E);

    // Layer 2: T2 = relu(A1)@Wl2 ; A2 = relu(A1)@Wr2 + bl2 ; A2[dst] += T2[src]*inv[dst]
    gemm_tiled<true, false><<<dim3(mb, 2), 256, 0, stream>>>(A1, Wl2, nullptr, T2, N, 256, 128);
    gemm_tiled<true, true ><<<dim3(mb, 2), 256, 0, stream>>>(A1, Wr2, bl2,     A2, N, 256, 128);
    scatter128<<<(E * 32 + 255) / 256, 256, 0, stream>>>(src, dst, inv, T2, A2, E);

    // Layer 3: t3 = relu(A2)@Wl3 ; out = relu(A2)@Wr3 + bl3 ; out[dst] += t3[src]*inv[dst]
    gemv_l3<<<(N * 64 + 255) / 256, 256, 0, stream>>>(A2, Wl3, Wr3, bl3, t3, out, N);
    scatter1<<<(E + 255) / 256, 256, 0, stream>>>(src, dst, inv, t3, out, E);
}

// Round 2
// 1366.273 us; speedup vs baseline: 6.5878x; 6.5878x over previous
//
#include <hip/hip_runtime.h>

// GraphSAGE 3-layer: N=100000, E=1.6M, dims 256->256->128->1.
// R2: replace per-feature float atomics (6.5 GB HBM write amplification, 5.3ms)
// with device-built CSR (sort-by-dst) + per-node gather (writes once per node).

// ---- CSR build ----------------------------------------------------------
__global__ __launch_bounds__(256) void count_deg(const int* __restrict__ dst,
                                                 int* __restrict__ deg, int E) {
    int e = blockIdx.x * blockDim.x + threadIdx.x;
    if (e < E) atomicAdd(&deg[dst[e]], 1);
}

// In-place exclusive scan over deg[] (chunk=1024/block), 3-phase.
__global__ __launch_bounds__(256) void scan_phaseA(int* __restrict__ a,
                                                   int* __restrict__ blockSums, int n) {
    __shared__ int sh[256];
    const int tid = threadIdx.x;
    const int base = blockIdx.x * 1024 + tid * 4;
    int v[4];
    #pragma unroll
    for (int i = 0; i < 4; ++i) v[i] = (base + i < n) ? a[base + i] : 0;
    int tsum = v[0] + v[1] + v[2] + v[3];
    sh[tid] = tsum;
    __syncthreads();
    for (int off = 1; off < 256; off <<= 1) {
        int t = (tid >= off) ? sh[tid - off] : 0;
        __syncthreads();
        sh[tid] += t;
        __syncthreads();
    }
    int run = sh[tid] - tsum;  // exclusive prefix of this thread's chunk
    #pragma unroll
    for (int i = 0; i < 4; ++i) {
        if (base + i < n) a[base + i] = run;
        run += v[i];
    }
    if (tid == 255) blockSums[blockIdx.x] = sh[255];
}

__global__ __launch_bounds__(256) void scan_phaseB(int* __restrict__ bs, int nb) {
    __shared__ int sh[256];
    const int tid = threadIdx.x;
    int v = (tid < nb) ? bs[tid] : 0;
    sh[tid] = v;
    __syncthreads();
    for (int off = 1; off < 256; off <<= 1) {
        int t = (tid >= off) ? sh[tid - off] : 0;
        __syncthreads();
        sh[tid] += t;
        __syncthreads();
    }
    if (tid < nb) bs[tid] = sh[tid] - v;  // exclusive
}

__global__ __launch_bounds__(256) void scan_phaseC(int* __restrict__ a,
                                                   const int* __restrict__ bs, int n) {
    const int base = blockIdx.x * 1024 + threadIdx.x * 4;
    const int add = bs[blockIdx.x];
    #pragma unroll
    for (int i = 0; i < 4; ++i)
        if (base + i < n) a[base + i] += add;
}

// cursor[] holds exclusive offsets on entry; on exit holds END offsets per node.
__global__ __launch_bounds__(256) void fill_csr(const int* __restrict__ src,
                                                const int* __restrict__ dst,
                                                int* __restrict__ cursor,
                                                int* __restrict__ csr, int E) {
    int e = blockIdx.x * blockDim.x + threadIdx.x;
    if (e < E) {
        int p = atomicAdd(&cursor[dst[e]], 1);
        csr[p] = src[e];
    }
}

__global__ __launch_bounds__(256) void inv_from_end(const int* __restrict__ endoff,
                                                    float* __restrict__ inv, int n) {
    int i = blockIdx.x * blockDim.x + threadIdx.x;
    if (i < n) {
        int end = endoff[i];
        int beg = i ? endoff[i - 1] : 0;
        inv[i] = 1.0f / fmaxf((float)(end - beg), 1.0f);
    }
}

// ---- GEMM (unchanged from R1) -------------------------------------------
template<bool RELU_X, bool BIAS>
__global__ __launch_bounds__(256) void gemm_tiled(
    const float* __restrict__ X, const float* __restrict__ W,
    const float* __restrict__ bias, float* __restrict__ Y,
    int M, int K, int H)
{
    __shared__ float Xs[16][64];
    __shared__ float Ws[16][64];
    const int tid = threadIdx.x;
    const int m0 = blockIdx.x * 64;
    const int h0 = blockIdx.y * 64;
    const int r = tid & 15;
    const int c = tid >> 4;
    const int lm  = tid >> 2;
    const int lk4 = (tid & 3) << 2;
    const int lkw = tid >> 4;
    const int lh4 = (tid & 15) << 2;

    float acc[4][4] = {{0.f,0.f,0.f,0.f},{0.f,0.f,0.f,0.f},
                       {0.f,0.f,0.f,0.f},{0.f,0.f,0.f,0.f}};

    for (int k0 = 0; k0 < K; k0 += 16) {
        float4 xv = make_float4(0.f, 0.f, 0.f, 0.f);
        const int gm = m0 + lm;
        if (gm < M) xv = *(const float4*)(X + (size_t)gm * K + k0 + lk4);
        if (RELU_X) {
            xv.x = fmaxf(xv.x, 0.f); xv.y = fmaxf(xv.y, 0.f);
            xv.z = fmaxf(xv.z, 0.f); xv.w = fmaxf(xv.w, 0.f);
        }
        Xs[lk4 + 0][lm] = xv.x;
        Xs[lk4 + 1][lm] = xv.y;
        Xs[lk4 + 2][lm] = xv.z;
        Xs[lk4 + 3][lm] = xv.w;
        *(float4*)(&Ws[lkw][lh4]) =
            *(const float4*)(W + (size_t)(k0 + lkw) * H + h0 + lh4);
        __syncthreads();
        #pragma unroll
        for (int k = 0; k < 16; ++k) {
            const float4 a = *(const float4*)(&Xs[k][r << 2]);
            const float4 b = *(const float4*)(&Ws[k][c << 2]);
            acc[0][0] += a.x * b.x; acc[0][1] += a.x * b.y;
            acc[0][2] += a.x * b.z; acc[0][3] += a.x * b.w;
            acc[1][0] += a.y * b.x; acc[1][1] += a.y * b.y;
            acc[1][2] += a.y * b.z; acc[1][3] += a.y * b.w;
            acc[2][0] += a.z * b.x; acc[2][1] += a.z * b.y;
            acc[2][2] += a.z * b.z; acc[2][3] += a.z * b.w;
            acc[3][0] += a.w * b.x; acc[3][1] += a.w * b.y;
            acc[3][2] += a.w * b.z; acc[3][3] += a.w * b.w;
        }
        __syncthreads();
    }

    float4 bv = make_float4(0.f, 0.f, 0.f, 0.f);
    if (BIAS) bv = *(const float4*)(bias + h0 + (c << 2));
    #pragma unroll
    for (int i = 0; i < 4; ++i) {
        const int gm = m0 + (r << 2) + i;
        if (gm >= M) continue;
        float4 o = make_float4(acc[i][0] + bv.x, acc[i][1] + bv.y,
                               acc[i][2] + bv.z, acc[i][3] + bv.w);
        *(float4*)(Y + (size_t)gm * H + h0 + (c << 2)) = o;
    }
}

// ---- Gather aggregation (one wave per dst node) -------------------------
// A[node] += inv[node] * sum_{s in nbrs(node)} T[s]   (feature dim 256, float4/lane)
__global__ __launch_bounds__(256) void agg256(
    const int* __restrict__ endoff, const int* __restrict__ csr,
    const float* __restrict__ inv, const float* __restrict__ T,
    float* __restrict__ A, int N)
{
    const int node = (int)((blockIdx.x * 256 + threadIdx.x) >> 6);
    const int lane = threadIdx.x & 63;
    if (node >= N) return;
    const int end = endoff[node];
    const int beg = node ? endoff[node - 1] : 0;
    float4 sum = make_float4(0.f, 0.f, 0.f, 0.f);
    int p = beg;
    for (; p + 4 <= end; p += 4) {
        const int s0 = csr[p], s1 = csr[p+1], s2 = csr[p+2], s3 = csr[p+3];
        const float4 v0 = *(const float4*)(T + (size_t)s0 * 256 + (lane << 2));
        const float4 v1 = *(const float4*)(T + (size_t)s1 * 256 + (lane << 2));
        const float4 v2 = *(const float4*)(T + (size_t)s2 * 256 + (lane << 2));
        const float4 v3 = *(const float4*)(T + (size_t)s3 * 256 + (lane << 2));
        sum.x += (v0.x + v1.x) + (v2.x + v3.x);
        sum.y += (v0.y + v1.y) + (v2.y + v3.y);
        sum.z += (v0.z + v1.z) + (v2.z + v3.z);
        sum.w += (v0.w + v1.w) + (v2.w + v3.w);
    }
    for (; p < end; ++p) {
        const float4 v = *(const float4*)(T + (size_t)csr[p] * 256 + (lane << 2));
        sum.x += v.x; sum.y += v.y; sum.z += v.z; sum.w += v.w;
    }
    const float w = inv[node];
    float* o = A + (size_t)node * 256 + (lane << 2);
    float4 a = *(const float4*)o;
    a.x += sum.x * w; a.y += sum.y * w; a.z += sum.z * w; a.w += sum.w * w;
    *(float4*)o = a;
}

// feature dim 128: float2 per lane
__global__ __launch_bounds__(256) void agg128(
    const int* __restrict__ endoff, const int* __restrict__ csr,
    const float* __restrict__ inv, const float* __restrict__ T,
    float* __restrict__ A, int N)
{
    const int node = (int)((blockIdx.x * 256 + threadIdx.x) >> 6);
    const int lane = threadIdx.x & 63;
    if (node >= N) return;
    const int end = endoff[node];
    const int beg = node ? endoff[node - 1] : 0;
    float2 sum = make_float2(0.f, 0.f);
    int p = beg;
    for (; p + 4 <= end; p += 4) {
        const int s0 = csr[p], s1 = csr[p+1], s2 = csr[p+2], s3 = csr[p+3];
        const float2 v0 = *(const float2*)(T + (size_t)s0 * 128 + (lane << 1));
        const float2 v1 = *(const float2*)(T + (size_t)s1 * 128 + (lane << 1));
        const float2 v2 = *(const float2*)(T + (size_t)s2 * 128 + (lane << 1));
        const float2 v3 = *(const float2*)(T + (size_t)s3 * 128 + (lane << 1));
        sum.x += (v0.x + v1.x) + (v2.x + v3.x);
        sum.y += (v0.y + v1.y) + (v2.y + v3.y);
    }
    for (; p < end; ++p) {
        const float2 v = *(const float2*)(T + (size_t)csr[p] * 128 + (lane << 1));
        sum.x += v.x; sum.y += v.y;
    }
    const float w = inv[node];
    float* o = A + (size_t)node * 128 + (lane << 1);
    float2 a = *(const float2*)o;
    a.x += sum.x * w; a.y += sum.y * w;
    *(float2*)o = a;
}

// Layer 3 transform: t3 = relu(A2)@Wl3 ; out = relu(A2)@Wr3 + b. One wave/node.
__global__ __launch_bounds__(256) void gemv_l3(
    const float* __restrict__ A2, const float* __restrict__ Wl,
    const float* __restrict__ Wr, const float* __restrict__ b,
    float* __restrict__ t3, float* __restrict__ out, int M)
{
    const int node = (int)((blockIdx.x * 256 + threadIdx.x) >> 6);
    const int lane = threadIdx.x & 63;
    if (node >= M) return;
    const float* row = A2 + (size_t)node * 128;
    const float a0 = fmaxf(row[lane], 0.f);
    const float a1 = fmaxf(row[64 + lane], 0.f);
    float dl = a0 * Wl[lane] + a1 * Wl[64 + lane];
    float dr = a0 * Wr[lane] + a1 * Wr[64 + lane];
    #pragma unroll
    for (int off = 32; off > 0; off >>= 1) {
        dl += __shfl_down(dl, off, 64);
        dr += __shfl_down(dr, off, 64);
    }
    if (lane == 0) {
        t3[node] = dl;
        out[node] = dr + b[0];
    }
}

// out[node] += inv[node] * sum t3[nbrs]; one thread per node (no atomics)
__global__ __launch_bounds__(256) void agg1(
    const int* __restrict__ endoff, const int* __restrict__ csr,
    const float* __restrict__ inv, const float* __restrict__ t3,
    float* __restrict__ out, int N)
{
    const int i = blockIdx.x * blockDim.x + threadIdx.x;
    if (i >= N) return;
    const int end = endoff[i];
    int p = i ? endoff[i - 1] : 0;
    float s = 0.f;
    for (; p + 4 <= end; p += 4)
        s += (t3[csr[p]] + t3[csr[p+1]]) + (t3[csr[p+2]] + t3[csr[p+3]]);
    for (; p < end; ++p) s += t3[csr[p]];
    out[i] += s * inv[i];
}

extern "C" void kernel_launch(void* const* d_in, const int* in_sizes, int n_in,
                              void* d_out, int out_size, void* d_ws, size_t ws_size,
                              hipStream_t stream) {
    const float* x   = (const float*)d_in[0];
    const int*   ei  = (const int*)d_in[1];
    const float* Wl1 = (const float*)d_in[2];
    const float* bl1 = (const float*)d_in[3];
    const float* Wr1 = (const float*)d_in[4];
    const float* Wl2 = (const float*)d_in[5];
    const float* bl2 = (const float*)d_in[6];
    const float* Wr2 = (const float*)d_in[7];
    const float* Wl3 = (const float*)d_in[8];
    const float* bl3 = (const float*)d_in[9];
    const float* Wr3 = (const float*)d_in[10];
    float* out = (float*)d_out;

    const int N = in_sizes[0] / 256;     // 100000
    const int E = in_sizes[1] / 2;       // 1600000
    const int* src = ei;
    const int* dst = ei + E;

    // workspace layout (4-byte elements)
    float* ws   = (float*)d_ws;
    float* A1   = ws;                                  // N*256
    float* T1   = A1 + (size_t)N * 256;                // N*256 (T2 = first half, A2 = second half)
    float* T2   = T1;
    float* A2   = T1 + (size_t)N * 128;
    float* t3   = T1 + (size_t)N * 256;                // N
    float* inv  = t3 + N;                              // N
    int*   endoff = (int*)(inv + N);                   // N (deg -> excl offsets -> end offsets)
    int*   bsums  = endoff + N;                        // 256
    int*   csr    = bsums + 256;                       // E
    // total ≈ 212.4 MB

    // ---- CSR build ----
    hipMemsetAsync(endoff, 0, (size_t)N * sizeof(int), stream);
    count_deg<<<(E + 255) / 256, 256, 0, stream>>>(dst, endoff, E);
    const int nScanBlocks = (N + 1023) / 1024;  // 98
    scan_phaseA<<<nScanBlocks, 256, 0, stream>>>(endoff, bsums, N);
    scan_phaseB<<<1, 256, 0, stream>>>(bsums, nScanBlocks);
    scan_phaseC<<<nScanBlocks, 256, 0, stream>>>(endoff, bsums, N);
    fill_csr<<<(E + 255) / 256, 256, 0, stream>>>(src, dst, endoff, csr, E);
    inv_from_end<<<(N + 255) / 256, 256, 0, stream>>>(endoff, inv, N);

    const int mb = (N + 63) / 64;  // 1563
    const int aggBlocks = (N * 64 + 255) / 256;  // 25000 (one wave per node)

    // Layer 1
    gemm_tiled<false, false><<<dim3(mb, 4), 256, 0, stream>>>(x, Wl1, nullptr, T1, N, 256, 256);
    gemm_tiled<false, true ><<<dim3(mb, 4), 256, 0, stream>>>(x, Wr1, bl1,     A1, N, 256, 256);
    agg256<<<aggBlocks, 256, 0, stream>>>(endoff, csr, inv, T1, A1, N);

    // Layer 2
    gemm_tiled<true, false><<<dim3(mb, 2), 256, 0, stream>>>(A1, Wl2, nullptr, T2, N, 256, 128);
    gemm_tiled<true, true ><<<dim3(mb, 2), 256, 0, stream>>>(A1, Wr2, bl2,     A2, N, 256, 128);
    agg128<<<aggBlocks, 256, 0, stream>>>(endoff, csr, inv, T2, A2, N);

    // Layer 3
    gemv_l3<<<aggBlocks, 256, 0, stream>>>(A2, Wl3, Wr3, bl3, t3, out, N);
    agg1<<<(N + 255) / 256, 256, 0, stream>>>(endoff, csr, inv, t3, out, N);
}

// Round 5
// 788.391 us; speedup vs baseline: 11.4166x; 1.7330x over previous
//
#include <hip/hip_runtime.h>
#include <hip/hip_bf16.h>

// GraphSAGE 3-layer, N=100000, E=1.6M, dims 256->256->128->1.
// R5: identical to R4 except the workspace aliasing bug is fixed.
// R3/R4 placed T2b at [25.6M,51.2M) INSIDE X2b=[0,51.2M) ([N][256] bf16!) ->
// layer-2 GEMM raced its own input (absmax ~0.37 on both, structurally
// identical failures). New layout: every kernel's writes are disjoint from
// all concurrently-live reads.

typedef __attribute__((ext_vector_type(8))) short short8;
typedef __attribute__((ext_vector_type(4))) float f32x4;

__device__ __forceinline__ unsigned short f2b(float f) {
    __hip_bfloat16 h = __float2bfloat16(f);
    return *reinterpret_cast<unsigned short*>(&h);
}
__device__ __forceinline__ float b2f(unsigned short u) {
    union { unsigned int i; float f; } v; v.i = ((unsigned int)u) << 16; return v.f;
}

// ---- prep: fp32 -> bf16 conversions -------------------------------------
__global__ __launch_bounds__(256) void convert_x(const float* __restrict__ x,
                                                 unsigned short* __restrict__ xb,
                                                 int total4) {
    int i = blockIdx.x * 256 + threadIdx.x;
    if (i >= total4) return;
    float4 v = *(const float4*)(x + (size_t)i * 4);
    ushort4 o;
    o.x = f2b(v.x); o.y = f2b(v.y); o.z = f2b(v.z); o.w = f2b(v.w);
    *(ushort4*)(xb + (size_t)i * 4) = o;
}

// W [K][H] fp32 -> Wsw [(K/8)][H][8] bf16 ; H = 1<<hs
__global__ __launch_bounds__(256) void prep_w(const float* __restrict__ W,
                                              unsigned short* __restrict__ out,
                                              int total, int hs) {
    int i = blockIdx.x * 256 + threadIdx.x;
    if (i >= total) return;
    int k = i >> hs;
    int h = i & ((1 << hs) - 1);
    out[((size_t)(((k >> 3) << hs) + h) << 3) + (k & 7)] = f2b(W[i]);
}

// ---- CSR build (unchanged) ----------------------------------------------
__global__ __launch_bounds__(256) void count_deg(const int* __restrict__ dst,
                                                 int* __restrict__ deg, int E) {
    int e = blockIdx.x * blockDim.x + threadIdx.x;
    if (e < E) atomicAdd(&deg[dst[e]], 1);
}

__global__ __launch_bounds__(256) void scan_phaseA(int* __restrict__ a,
                                                   int* __restrict__ blockSums, int n) {
    __shared__ int sh[256];
    const int tid = threadIdx.x;
    const int base = blockIdx.x * 1024 + tid * 4;
    int v[4];
    #pragma unroll
    for (int i = 0; i < 4; ++i) v[i] = (base + i < n) ? a[base + i] : 0;
    int tsum = v[0] + v[1] + v[2] + v[3];
    sh[tid] = tsum;
    __syncthreads();
    for (int off = 1; off < 256; off <<= 1) {
        int t = (tid >= off) ? sh[tid - off] : 0;
        __syncthreads();
        sh[tid] += t;
        __syncthreads();
    }
    int run = sh[tid] - tsum;
    #pragma unroll
    for (int i = 0; i < 4; ++i) {
        if (base + i < n) a[base + i] = run;
        run += v[i];
    }
    if (tid == 255) blockSums[blockIdx.x] = sh[255];
}

__global__ __launch_bounds__(256) void scan_phaseB(int* __restrict__ bs, int nb) {
    __shared__ int sh[256];
    const int tid = threadIdx.x;
    int v = (tid < nb) ? bs[tid] : 0;
    sh[tid] = v;
    __syncthreads();
    for (int off = 1; off < 256; off <<= 1) {
        int t = (tid >= off) ? sh[tid - off] : 0;
        __syncthreads();
        sh[tid] += t;
        __syncthreads();
    }
    if (tid < nb) bs[tid] = sh[tid] - v;
}

__global__ __launch_bounds__(256) void scan_phaseC(int* __restrict__ a,
                                                   const int* __restrict__ bs, int n) {
    const int base = blockIdx.x * 1024 + threadIdx.x * 4;
    const int add = bs[blockIdx.x];
    #pragma unroll
    for (int i = 0; i < 4; ++i)
        if (base + i < n) a[base + i] += add;
}

__global__ __launch_bounds__(256) void fill_csr(const int* __restrict__ src,
                                                const int* __restrict__ dst,
                                                int* __restrict__ cursor,
                                                int* __restrict__ csr, int E) {
    int e = blockIdx.x * blockDim.x + threadIdx.x;
    if (e < E) {
        int p = atomicAdd(&cursor[dst[e]], 1);
        csr[p] = src[e];
    }
}

__global__ __launch_bounds__(256) void inv_from_end(const int* __restrict__ endoff,
                                                    float* __restrict__ inv, int n) {
    int i = blockIdx.x * blockDim.x + threadIdx.x;
    if (i < n) {
        int end = endoff[i];
        int beg = i ? endoff[i - 1] : 0;
        inv[i] = 1.0f / fmaxf((float)(end - beg), 1.0f);
    }
}

// ---- bf16 MFMA GEMM, LDS-free (R4, K=256 fixed — correct for both layers:
// layer1 in-dim 256, layer2 in-dim h1=256) --------------------------------
// Xb [M][256] bf16 row-major. Wsw [(256/8)][H][8] bf16.
// Block = 4 waves; wave w computes rows [blockIdx.x*256 + w*64, +64) x 64 cols.
// grid.y in [0, 2*H/64): first H/64 -> Wl path (Tout bf16), rest -> Wr path
// (Abase fp32 = X@Wr + bias).
// Fragment layouts (HW-verified):
//   A: lane holds A[m = lane&15][k = (lane>>4)*8 + j], j=0..7
//   B: lane holds B[k = (lane>>4)*8 + j][n = lane&15]
//   D: col = lane&15, row = (lane>>4)*4 + reg
__global__ __launch_bounds__(256) void gemm_bf16(
    const unsigned short* __restrict__ Xb,
    const unsigned short* __restrict__ Wsw_l,
    const unsigned short* __restrict__ Wsw_r,
    const float* __restrict__ bias,
    unsigned short* __restrict__ Tout,
    float* __restrict__ Abase,
    int M, int H)
{
    const int tid = threadIdx.x;
    const int wid = tid >> 6;
    const int lane = tid & 63;
    const int quad = lane >> 4;
    const int l15 = lane & 15;

    const int nW = H >> 6;
    const bool is_l = (int)blockIdx.y < nW;
    const int yb = is_l ? blockIdx.y : (int)blockIdx.y - nW;
    const int col0 = yb << 6;
    const unsigned short* Wsw = is_l ? Wsw_l : Wsw_r;
    const int m0 = blockIdx.x * 256 + wid * 64;

    const unsigned short* aptr[4];
    #pragma unroll
    for (int mt = 0; mt < 4; ++mt) {
        int r = m0 + mt * 16 + l15;
        if (r > M - 1) r = M - 1;
        aptr[mt] = Xb + ((size_t)r << 8) + (quad << 3);
    }
    const unsigned short* bptr[4];
    #pragma unroll
    for (int nt = 0; nt < 4; ++nt) {
        const int col = col0 + nt * 16 + l15;
        bptr[nt] = Wsw + (((size_t)quad * H + col) << 3);
    }

    const f32x4 zero = {0.f, 0.f, 0.f, 0.f};
    f32x4 acc[4][4];
    #pragma unroll
    for (int mt = 0; mt < 4; ++mt)
        #pragma unroll
        for (int nt = 0; nt < 4; ++nt) acc[mt][nt] = zero;

    #pragma unroll 2
    for (int ks = 0; ks < 8; ++ks) {          // k32 = ks*32, K = 256
        short8 af[4], bf[4];
        #pragma unroll
        for (int mt = 0; mt < 4; ++mt)
            af[mt] = *(const short8*)(aptr[mt] + ks * 32);
        #pragma unroll
        for (int nt = 0; nt < 4; ++nt)
            bf[nt] = *(const short8*)(bptr[nt] + (size_t)ks * 32 * H);
        #pragma unroll
        for (int mt = 0; mt < 4; ++mt)
            #pragma unroll
            for (int nt = 0; nt < 4; ++nt)
                acc[mt][nt] = __builtin_amdgcn_mfma_f32_16x16x32_bf16(
                    af[mt], bf[nt], acc[mt][nt], 0, 0, 0);
    }

    #pragma unroll
    for (int nt = 0; nt < 4; ++nt) {
        const int colg = col0 + nt * 16 + l15;
        if (is_l) {
            #pragma unroll
            for (int mt = 0; mt < 4; ++mt) {
                const int gmb = m0 + mt * 16 + quad * 4;
                #pragma unroll
                for (int r = 0; r < 4; ++r)
                    if (gmb + r < M)
                        Tout[(size_t)(gmb + r) * H + colg] = f2b(acc[mt][nt][r]);
            }
        } else {
            const float bb = bias[colg];
            #pragma unroll
            for (int mt = 0; mt < 4; ++mt) {
                const int gmb = m0 + mt * 16 + quad * 4;
                #pragma unroll
                for (int r = 0; r < 4; ++r)
                    if (gmb + r < M)
                        Abase[(size_t)(gmb + r) * H + colg] = acc[mt][nt][r] + bb;
            }
        }
    }
}

// ---- aggregation: mean-gather bf16 T, add fp32 base, relu, write bf16 ----
__global__ __launch_bounds__(256) void agg256_b(
    const int* __restrict__ endoff, const int* __restrict__ csr,
    const float* __restrict__ inv, const unsigned short* __restrict__ T,
    const float* __restrict__ Abase, unsigned short* __restrict__ Xout, int N)
{
    const int node = (int)((blockIdx.x * 256 + threadIdx.x) >> 6);
    const int lane = threadIdx.x & 63;
    if (node >= N) return;
    const int end = endoff[node];
    const int beg = node ? endoff[node - 1] : 0;
    float s0 = 0.f, s1 = 0.f, s2 = 0.f, s3 = 0.f;
    int p = beg;
    for (; p + 4 <= end; p += 4) {
        const int a = csr[p], b = csr[p + 1], c = csr[p + 2], d = csr[p + 3];
        ushort4 v0 = *(const ushort4*)(T + ((size_t)a << 8) + (lane << 2));
        ushort4 v1 = *(const ushort4*)(T + ((size_t)b << 8) + (lane << 2));
        ushort4 v2 = *(const ushort4*)(T + ((size_t)c << 8) + (lane << 2));
        ushort4 v3 = *(const ushort4*)(T + ((size_t)d << 8) + (lane << 2));
        s0 += (b2f(v0.x) + b2f(v1.x)) + (b2f(v2.x) + b2f(v3.x));
        s1 += (b2f(v0.y) + b2f(v1.y)) + (b2f(v2.y) + b2f(v3.y));
        s2 += (b2f(v0.z) + b2f(v1.z)) + (b2f(v2.z) + b2f(v3.z));
        s3 += (b2f(v0.w) + b2f(v1.w)) + (b2f(v2.w) + b2f(v3.w));
    }
    for (; p < end; ++p) {
        ushort4 v = *(const ushort4*)(T + ((size_t)csr[p] << 8) + (lane << 2));
        s0 += b2f(v.x); s1 += b2f(v.y); s2 += b2f(v.z); s3 += b2f(v.w);
    }
    const float w = inv[node];
    const float4 base = *(const float4*)(Abase + ((size_t)node << 8) + (lane << 2));
    ushort4 o;
    o.x = f2b(fmaxf(base.x + s0 * w, 0.f));
    o.y = f2b(fmaxf(base.y + s1 * w, 0.f));
    o.z = f2b(fmaxf(base.z + s2 * w, 0.f));
    o.w = f2b(fmaxf(base.w + s3 * w, 0.f));
    *(ushort4*)(Xout + ((size_t)node << 8) + (lane << 2)) = o;
}

__global__ __launch_bounds__(256) void agg128_b(
    const int* __restrict__ endoff, const int* __restrict__ csr,
    const float* __restrict__ inv, const unsigned short* __restrict__ T,
    const float* __restrict__ Abase, unsigned short* __restrict__ Xout, int N)
{
    const int node = (int)((blockIdx.x * 256 + threadIdx.x) >> 5);
    const int lane = threadIdx.x & 31;
    if (node >= N) return;
    const int end = endoff[node];
    const int beg = node ? endoff[node - 1] : 0;
    float s0 = 0.f, s1 = 0.f, s2 = 0.f, s3 = 0.f;
    int p = beg;
    for (; p + 4 <= end; p += 4) {
        const int a = csr[p], b = csr[p + 1], c = csr[p + 2], d = csr[p + 3];
        ushort4 v0 = *(const ushort4*)(T + ((size_t)a << 7) + (lane << 2));
        ushort4 v1 = *(const ushort4*)(T + ((size_t)b << 7) + (lane << 2));
        ushort4 v2 = *(const ushort4*)(T + ((size_t)c << 7) + (lane << 2));
        ushort4 v3 = *(const ushort4*)(T + ((size_t)d << 7) + (lane << 2));
        s0 += (b2f(v0.x) + b2f(v1.x)) + (b2f(v2.x) + b2f(v3.x));
        s1 += (b2f(v0.y) + b2f(v1.y)) + (b2f(v2.y) + b2f(v3.y));
        s2 += (b2f(v0.z) + b2f(v1.z)) + (b2f(v2.z) + b2f(v3.z));
        s3 += (b2f(v0.w) + b2f(v1.w)) + (b2f(v2.w) + b2f(v3.w));
    }
    for (; p < end; ++p) {
        ushort4 v = *(const ushort4*)(T + ((size_t)csr[p] << 7) + (lane << 2));
        s0 += b2f(v.x); s1 += b2f(v.y); s2 += b2f(v.z); s3 += b2f(v.w);
    }
    const float w = inv[node];
    const float4 base = *(const float4*)(Abase + ((size_t)node << 7) + (lane << 2));
    ushort4 o;
    o.x = f2b(fmaxf(base.x + s0 * w, 0.f));
    o.y = f2b(fmaxf(base.y + s1 * w, 0.f));
    o.z = f2b(fmaxf(base.z + s2 * w, 0.f));
    o.w = f2b(fmaxf(base.w + s3 * w, 0.f));
    *(ushort4*)(Xout + ((size_t)node << 7) + (lane << 2)) = o;
}

// Layer 3: t3 = X3@Wl3 ; out = X3@Wr3 + b. X3 already relu'd bf16. One wave/node.
__global__ __launch_bounds__(256) void gemv_l3(
    const unsigned short* __restrict__ X3, const float* __restrict__ Wl,
    const float* __restrict__ Wr, const float* __restrict__ b,
    float* __restrict__ t3, float* __restrict__ out, int M)
{
    const int node = (int)((blockIdx.x * 256 + threadIdx.x) >> 6);
    const int lane = threadIdx.x & 63;
    if (node >= M) return;
    const unsigned short* row = X3 + ((size_t)node << 7);
    const float a0 = b2f(row[lane]);
    const float a1 = b2f(row[64 + lane]);
    float dl = a0 * Wl[lane] + a1 * Wl[64 + lane];
    float dr = a0 * Wr[lane] + a1 * Wr[64 + lane];
    #pragma unroll
    for (int off = 32; off > 0; off >>= 1) {
        dl += __shfl_down(dl, off, 64);
        dr += __shfl_down(dr, off, 64);
    }
    if (lane == 0) {
        t3[node] = dl;
        out[node] = dr + b[0];
    }
}

__global__ __launch_bounds__(256) void agg1(
    const int* __restrict__ endoff, const int* __restrict__ csr,
    const float* __restrict__ inv, const float* __restrict__ t3,
    float* __restrict__ out, int N)
{
    const int i = blockIdx.x * blockDim.x + threadIdx.x;
    if (i >= N) return;
    const int end = endoff[i];
    int p = i ? endoff[i - 1] : 0;
    float s = 0.f;
    for (; p + 4 <= end; p += 4)
        s += (t3[csr[p]] + t3[csr[p + 1]]) + (t3[csr[p + 2]] + t3[csr[p + 3]]);
    for (; p < end; ++p) s += t3[csr[p]];
    out[i] += s * inv[i];
}

extern "C" void kernel_launch(void* const* d_in, const int* in_sizes, int n_in,
                              void* d_out, int out_size, void* d_ws, size_t ws_size,
                              hipStream_t stream) {
    const float* x   = (const float*)d_in[0];
    const int*   ei  = (const int*)d_in[1];
    const float* Wl1 = (const float*)d_in[2];
    const float* bl1 = (const float*)d_in[3];
    const float* Wr1 = (const float*)d_in[4];
    const float* Wl2 = (const float*)d_in[5];
    const float* bl2 = (const float*)d_in[6];
    const float* Wr2 = (const float*)d_in[7];
    const float* Wl3 = (const float*)d_in[8];
    const float* bl3 = (const float*)d_in[9];
    const float* Wr3 = (const float*)d_in[10];
    float* out = (float*)d_out;

    const int N = in_sizes[0] / 256;   // 100000
    const int E = in_sizes[1] / 2;     // 1600000
    const int* src = ei;
    const int* dst = ei + E;

    // ---- workspace layout (bytes), race-free aliasing --------------------
    // Live-range audit (writes never overlap concurrently-read regions):
    //   convert_x:  W X1b[0,51.2)
    //   L1 gemm:    R X1b[0,51.2)        W T1b[51.2,102.4)  W A1b[102.4,204.8)
    //   agg256_b:   R T1b,A1b            W X2b[0,51.2)      (X1b dead)
    //   L2 gemm:    R X2b[0,51.2)        W T2b[51.2,76.8)   W A2b[76.8,128.0)
    //                                    (T1b/A1b dead)
    //   agg128_b:   R T2b,A2b            W X3b[0,25.6)      (X2b dead)
    //   gemv_l3:    R X3b                W t3,out
    //   agg1:       R t3                 RW out
    char* W = (char*)d_ws;
    const size_t MB512 = (size_t)100000 * 512;   // N*256 bf16 bytes = 51.2MB
    unsigned short* X1b = (unsigned short*)(W);
    unsigned short* T1b = (unsigned short*)(W + MB512);
    float*          A1b = (float*)(W + 2 * MB512);
    unsigned short* X2b = (unsigned short*)(W);                 // over dead X1b
    unsigned short* T2b = (unsigned short*)(W + MB512);         // over dead T1b
    float*          A2b = (float*)(W + MB512 + MB512 / 2);      // [76.8M,128.0M)
    unsigned short* X3b = (unsigned short*)(W);                 // over dead X2b
    char* S = W + 4 * MB512;                                    // smalls @ 204.8M
    float* inv    = (float*)(S);
    int*   endoff = (int*)(S + (size_t)N * 4);
    int*   bsums  = (int*)(S + (size_t)N * 8);
    float* t3     = (float*)(S + (size_t)N * 8 + 1024);
    int*   csr    = (int*)(S + (size_t)N * 12 + 1024);
    unsigned short* Wl1s = (unsigned short*)(S + (size_t)N * 12 + 1024 + (size_t)E * 4);
    unsigned short* Wr1s = Wl1s + 65536;
    unsigned short* Wl2s = Wr1s + 65536;
    unsigned short* Wr2s = Wl2s + 32768;

    // ---- prep: conversions + CSR ----
    convert_x<<<(N * 64 + 255) / 256, 256, 0, stream>>>(x, X1b, N * 64);
    prep_w<<<(65536 + 255) / 256, 256, 0, stream>>>(Wl1, Wl1s, 65536, 8);
    prep_w<<<(65536 + 255) / 256, 256, 0, stream>>>(Wr1, Wr1s, 65536, 8);
    prep_w<<<(32768 + 255) / 256, 256, 0, stream>>>(Wl2, Wl2s, 32768, 7);
    prep_w<<<(32768 + 255) / 256, 256, 0, stream>>>(Wr2, Wr2s, 32768, 7);

    hipMemsetAsync(endoff, 0, (size_t)N * sizeof(int), stream);
    count_deg<<<(E + 255) / 256, 256, 0, stream>>>(dst, endoff, E);
    const int nScanBlocks = (N + 1023) / 1024;
    scan_phaseA<<<nScanBlocks, 256, 0, stream>>>(endoff, bsums, N);
    scan_phaseB<<<1, 256, 0, stream>>>(bsums, nScanBlocks);
    scan_phaseC<<<nScanBlocks, 256, 0, stream>>>(endoff, bsums, N);
    fill_csr<<<(E + 255) / 256, 256, 0, stream>>>(src, dst, endoff, csr, E);
    inv_from_end<<<(N + 255) / 256, 256, 0, stream>>>(endoff, inv, N);

    const int gx = (N + 255) / 256;  // 391

    // Layer 1: T1b = bf16(X@Wl1) ; A1b = X@Wr1 + bl1 ; agg -> X2b = bf16(relu(.))
    gemm_bf16<<<dim3(gx, 8), 256, 0, stream>>>(X1b, Wl1s, Wr1s, bl1, T1b, A1b, N, 256);
    agg256_b<<<(N * 64 + 255) / 256, 256, 0, stream>>>(endoff, csr, inv, T1b, A1b, X2b, N);

    // Layer 2 (K=256: h1=256)
    gemm_bf16<<<dim3(gx, 4), 256, 0, stream>>>(X2b, Wl2s, Wr2s, bl2, T2b, A2b, N, 128);
    agg128_b<<<(N * 32 + 255) / 256, 256, 0, stream>>>(endoff, csr, inv, T2b, A2b, X3b, N);

    // Layer 3
    gemv_l3<<<(N * 64 + 255) / 256, 256, 0, stream>>>(X3b, Wl3, Wr3, bl3, t3, out, N);
    agg1<<<(N + 255) / 256, 256, 0, stream>>>(endoff, csr, inv, t3, out, N);
}

// Round 6
// 730.784 us; speedup vs baseline: 12.3165x; 1.0788x over previous
//
#include <hip/hip_runtime.h>
#include <hip/hip_bf16.h>

// GraphSAGE 3-layer, N=100000, E=1.6M, dims 256->256->128->1.
// R6: cut GEMM HBM traffic. R5's gemm was memory-bound (456MB traffic, 40%
// HBM peak): X re-read 8x with poor L3 temporal locality, Abase fp32.
// Changes: (a) fuse Wl+Wr into one block (X read serves both), (b) col-block
// = fast grid dim so X-sharing siblings are co-resident, (c) Abase in bf16.

typedef __attribute__((ext_vector_type(8))) short short8;
typedef __attribute__((ext_vector_type(4))) float f32x4;

__device__ __forceinline__ unsigned short f2b(float f) {
    __hip_bfloat16 h = __float2bfloat16(f);
    return *reinterpret_cast<unsigned short*>(&h);
}
__device__ __forceinline__ float b2f(unsigned short u) {
    union { unsigned int i; float f; } v; v.i = ((unsigned int)u) << 16; return v.f;
}

// ---- prep: fp32 -> bf16 conversions -------------------------------------
__global__ __launch_bounds__(256) void convert_x(const float* __restrict__ x,
                                                 unsigned short* __restrict__ xb,
                                                 int total4) {
    int i = blockIdx.x * 256 + threadIdx.x;
    if (i >= total4) return;
    float4 v = *(const float4*)(x + (size_t)i * 4);
    ushort4 o;
    o.x = f2b(v.x); o.y = f2b(v.y); o.z = f2b(v.z); o.w = f2b(v.w);
    *(ushort4*)(xb + (size_t)i * 4) = o;
}

// W [K][H] fp32 -> Wsw [(K/8)][H][8] bf16 ; H = 1<<hs
__global__ __launch_bounds__(256) void prep_w(const float* __restrict__ W,
                                              unsigned short* __restrict__ out,
                                              int total, int hs) {
    int i = blockIdx.x * 256 + threadIdx.x;
    if (i >= total) return;
    int k = i >> hs;
    int h = i & ((1 << hs) - 1);
    out[((size_t)(((k >> 3) << hs) + h) << 3) + (k & 7)] = f2b(W[i]);
}

// ---- CSR build (unchanged) ----------------------------------------------
__global__ __launch_bounds__(256) void count_deg(const int* __restrict__ dst,
                                                 int* __restrict__ deg, int E) {
    int e = blockIdx.x * blockDim.x + threadIdx.x;
    if (e < E) atomicAdd(&deg[dst[e]], 1);
}

__global__ __launch_bounds__(256) void scan_phaseA(int* __restrict__ a,
                                                   int* __restrict__ blockSums, int n) {
    __shared__ int sh[256];
    const int tid = threadIdx.x;
    const int base = blockIdx.x * 1024 + tid * 4;
    int v[4];
    #pragma unroll
    for (int i = 0; i < 4; ++i) v[i] = (base + i < n) ? a[base + i] : 0;
    int tsum = v[0] + v[1] + v[2] + v[3];
    sh[tid] = tsum;
    __syncthreads();
    for (int off = 1; off < 256; off <<= 1) {
        int t = (tid >= off) ? sh[tid - off] : 0;
        __syncthreads();
        sh[tid] += t;
        __syncthreads();
    }
    int run = sh[tid] - tsum;
    #pragma unroll
    for (int i = 0; i < 4; ++i) {
        if (base + i < n) a[base + i] = run;
        run += v[i];
    }
    if (tid == 255) blockSums[blockIdx.x] = sh[255];
}

__global__ __launch_bounds__(256) void scan_phaseB(int* __restrict__ bs, int nb) {
    __shared__ int sh[256];
    const int tid = threadIdx.x;
    int v = (tid < nb) ? bs[tid] : 0;
    sh[tid] = v;
    __syncthreads();
    for (int off = 1; off < 256; off <<= 1) {
        int t = (tid >= off) ? sh[tid - off] : 0;
        __syncthreads();
        sh[tid] += t;
        __syncthreads();
    }
    if (tid < nb) bs[tid] = sh[tid] - v;
}

__global__ __launch_bounds__(256) void scan_phaseC(int* __restrict__ a,
                                                   const int* __restrict__ bs, int n) {
    const int base = blockIdx.x * 1024 + threadIdx.x * 4;
    const int add = bs[blockIdx.x];
    #pragma unroll
    for (int i = 0; i < 4; ++i)
        if (base + i < n) a[base + i] += add;
}

__global__ __launch_bounds__(256) void fill_csr(const int* __restrict__ src,
                                                const int* __restrict__ dst,
                                                int* __restrict__ cursor,
                                                int* __restrict__ csr, int E) {
    int e = blockIdx.x * blockDim.x + threadIdx.x;
    if (e < E) {
        int p = atomicAdd(&cursor[dst[e]], 1);
        csr[p] = src[e];
    }
}

__global__ __launch_bounds__(256) void inv_from_end(const int* __restrict__ endoff,
                                                    float* __restrict__ inv, int n) {
    int i = blockIdx.x * blockDim.x + threadIdx.x;
    if (i < n) {
        int end = endoff[i];
        int beg = i ? endoff[i - 1] : 0;
        inv[i] = 1.0f / fmaxf((float)(end - beg), 1.0f);
    }
}

// ---- fused bf16 MFMA GEMM, LDS-free (K=256 fixed) -----------------------
// Xb [M][256] bf16. Wsw_{l,r} [(256/8)][H][8] bf16.
// Block = 4 waves x 32 rows = 128 rows; covers ONE 64-col block of BOTH
// weights (Wl -> Tout bf16, Wr+bias -> Abase bf16). blockIdx.x = col-block
// (fast dim -> X-sharing siblings co-resident), blockIdx.y = row-block.
// Fragment layouts (HW-verified):
//   A: lane holds A[m = lane&15][k = (lane>>4)*8 + j]
//   B: lane holds B[k = (lane>>4)*8 + j][n = lane&15]
//   D: col = lane&15, row = (lane>>4)*4 + reg
__global__ __launch_bounds__(256) void gemm_bf16(
    const unsigned short* __restrict__ Xb,
    const unsigned short* __restrict__ Wsw_l,
    const unsigned short* __restrict__ Wsw_r,
    const float* __restrict__ bias,
    unsigned short* __restrict__ Tout,
    unsigned short* __restrict__ Abase,
    int M, int H)
{
    const int tid = threadIdx.x;
    const int wid = tid >> 6;
    const int lane = tid & 63;
    const int quad = lane >> 4;
    const int l15 = lane & 15;

    const int col0 = blockIdx.x << 6;
    const int m0 = blockIdx.y * 128 + wid * 32;

    const unsigned short* aptr[2];
    #pragma unroll
    for (int mt = 0; mt < 2; ++mt) {
        int r = m0 + mt * 16 + l15;
        if (r > M - 1) r = M - 1;
        aptr[mt] = Xb + ((size_t)r << 8) + (quad << 3);
    }
    const unsigned short* bptr[8];   // 0..3 = Wl, 4..7 = Wr
    #pragma unroll
    for (int nt = 0; nt < 4; ++nt) {
        const int col = col0 + nt * 16 + l15;
        bptr[nt]     = Wsw_l + (((size_t)quad * H + col) << 3);
        bptr[nt + 4] = Wsw_r + (((size_t)quad * H + col) << 3);
    }

    const f32x4 zero = {0.f, 0.f, 0.f, 0.f};
    f32x4 acc[2][8];
    #pragma unroll
    for (int mt = 0; mt < 2; ++mt)
        #pragma unroll
        for (int nt = 0; nt < 8; ++nt) acc[mt][nt] = zero;

    #pragma unroll 2
    for (int ks = 0; ks < 8; ++ks) {          // k32 = ks*32, K = 256
        short8 af[2], bf[8];
        #pragma unroll
        for (int mt = 0; mt < 2; ++mt)
            af[mt] = *(const short8*)(aptr[mt] + ks * 32);
        #pragma unroll
        for (int nt = 0; nt < 8; ++nt)
            bf[nt] = *(const short8*)(bptr[nt] + (size_t)ks * 32 * H);
        #pragma unroll
        for (int mt = 0; mt < 2; ++mt)
            #pragma unroll
            for (int nt = 0; nt < 8; ++nt)
                acc[mt][nt] = __builtin_amdgcn_mfma_f32_16x16x32_bf16(
                    af[mt], bf[nt], acc[mt][nt], 0, 0, 0);
    }

    #pragma unroll
    for (int nt = 0; nt < 4; ++nt) {
        const int colg = col0 + nt * 16 + l15;
        const float bb = bias[colg];
        #pragma unroll
        for (int mt = 0; mt < 2; ++mt) {
            const int gmb = m0 + mt * 16 + quad * 4;
            #pragma unroll
            for (int r = 0; r < 4; ++r) {
                if (gmb + r < M) {
                    Tout [(size_t)(gmb + r) * H + colg] = f2b(acc[mt][nt][r]);
                    Abase[(size_t)(gmb + r) * H + colg] = f2b(acc[mt][nt + 4][r] + bb);
                }
            }
        }
    }
}

// ---- aggregation: mean-gather bf16 T, add bf16 base, relu, write bf16 ---
__global__ __launch_bounds__(256) void agg256_b(
    const int* __restrict__ endoff, const int* __restrict__ csr,
    const float* __restrict__ inv, const unsigned short* __restrict__ T,
    const unsigned short* __restrict__ Abase, unsigned short* __restrict__ Xout, int N)
{
    const int node = (int)((blockIdx.x * 256 + threadIdx.x) >> 6);
    const int lane = threadIdx.x & 63;
    if (node >= N) return;
    const int end = endoff[node];
    const int beg = node ? endoff[node - 1] : 0;
    float s0 = 0.f, s1 = 0.f, s2 = 0.f, s3 = 0.f;
    int p = beg;
    for (; p + 4 <= end; p += 4) {
        const int a = csr[p], b = csr[p + 1], c = csr[p + 2], d = csr[p + 3];
        ushort4 v0 = *(const ushort4*)(T + ((size_t)a << 8) + (lane << 2));
        ushort4 v1 = *(const ushort4*)(T + ((size_t)b << 8) + (lane << 2));
        ushort4 v2 = *(const ushort4*)(T + ((size_t)c << 8) + (lane << 2));
        ushort4 v3 = *(const ushort4*)(T + ((size_t)d << 8) + (lane << 2));
        s0 += (b2f(v0.x) + b2f(v1.x)) + (b2f(v2.x) + b2f(v3.x));
        s1 += (b2f(v0.y) + b2f(v1.y)) + (b2f(v2.y) + b2f(v3.y));
        s2 += (b2f(v0.z) + b2f(v1.z)) + (b2f(v2.z) + b2f(v3.z));
        s3 += (b2f(v0.w) + b2f(v1.w)) + (b2f(v2.w) + b2f(v3.w));
    }
    for (; p < end; ++p) {
        ushort4 v = *(const ushort4*)(T + ((size_t)csr[p] << 8) + (lane << 2));
        s0 += b2f(v.x); s1 += b2f(v.y); s2 += b2f(v.z); s3 += b2f(v.w);
    }
    const float w = inv[node];
    const ushort4 bu = *(const ushort4*)(Abase + ((size_t)node << 8) + (lane << 2));
    ushort4 o;
    o.x = f2b(fmaxf(b2f(bu.x) + s0 * w, 0.f));
    o.y = f2b(fmaxf(b2f(bu.y) + s1 * w, 0.f));
    o.z = f2b(fmaxf(b2f(bu.z) + s2 * w, 0.f));
    o.w = f2b(fmaxf(b2f(bu.w) + s3 * w, 0.f));
    *(ushort4*)(Xout + ((size_t)node << 8) + (lane << 2)) = o;
}

__global__ __launch_bounds__(256) void agg128_b(
    const int* __restrict__ endoff, const int* __restrict__ csr,
    const float* __restrict__ inv, const unsigned short* __restrict__ T,
    const unsigned short* __restrict__ Abase, unsigned short* __restrict__ Xout, int N)
{
    const int node = (int)((blockIdx.x * 256 + threadIdx.x) >> 5);
    const int lane = threadIdx.x & 31;
    if (node >= N) return;
    const int end = endoff[node];
    const int beg = node ? endoff[node - 1] : 0;
    float s0 = 0.f, s1 = 0.f, s2 = 0.f, s3 = 0.f;
    int p = beg;
    for (; p + 4 <= end; p += 4) {
        const int a = csr[p], b = csr[p + 1], c = csr[p + 2], d = csr[p + 3];
        ushort4 v0 = *(const ushort4*)(T + ((size_t)a << 7) + (lane << 2));
        ushort4 v1 = *(const ushort4*)(T + ((size_t)b << 7) + (lane << 2));
        ushort4 v2 = *(const ushort4*)(T + ((size_t)c << 7) + (lane << 2));
        ushort4 v3 = *(const ushort4*)(T + ((size_t)d << 7) + (lane << 2));
        s0 += (b2f(v0.x) + b2f(v1.x)) + (b2f(v2.x) + b2f(v3.x));
        s1 += (b2f(v0.y) + b2f(v1.y)) + (b2f(v2.y) + b2f(v3.y));
        s2 += (b2f(v0.z) + b2f(v1.z)) + (b2f(v2.z) + b2f(v3.z));
        s3 += (b2f(v0.w) + b2f(v1.w)) + (b2f(v2.w) + b2f(v3.w));
    }
    for (; p < end; ++p) {
        ushort4 v = *(const ushort4*)(T + ((size_t)csr[p] << 7) + (lane << 2));
        s0 += b2f(v.x); s1 += b2f(v.y); s2 += b2f(v.z); s3 += b2f(v.w);
    }
    const float w = inv[node];
    const ushort4 bu = *(const ushort4*)(Abase + ((size_t)node << 7) + (lane << 2));
    ushort4 o;
    o.x = f2b(fmaxf(b2f(bu.x) + s0 * w, 0.f));
    o.y = f2b(fmaxf(b2f(bu.y) + s1 * w, 0.f));
    o.z = f2b(fmaxf(b2f(bu.z) + s2 * w, 0.f));
    o.w = f2b(fmaxf(b2f(bu.w) + s3 * w, 0.f));
    *(ushort4*)(Xout + ((size_t)node << 7) + (lane << 2)) = o;
}

// Layer 3: t3 = X3@Wl3 ; out = X3@Wr3 + b. One wave/node, K=128.
__global__ __launch_bounds__(256) void gemv_l3(
    const unsigned short* __restrict__ X3, const float* __restrict__ Wl,
    const float* __restrict__ Wr, const float* __restrict__ b,
    float* __restrict__ t3, float* __restrict__ out, int M)
{
    const int node = (int)((blockIdx.x * 256 + threadIdx.x) >> 6);
    const int lane = threadIdx.x & 63;
    if (node >= M) return;
    const unsigned short* row = X3 + ((size_t)node << 7);
    const float a0 = b2f(row[lane]);
    const float a1 = b2f(row[64 + lane]);
    float dl = a0 * Wl[lane] + a1 * Wl[64 + lane];
    float dr = a0 * Wr[lane] + a1 * Wr[64 + lane];
    #pragma unroll
    for (int off = 32; off > 0; off >>= 1) {
        dl += __shfl_down(dl, off, 64);
        dr += __shfl_down(dr, off, 64);
    }
    if (lane == 0) {
        t3[node] = dl;
        out[node] = dr + b[0];
    }
}

__global__ __launch_bounds__(256) void agg1(
    const int* __restrict__ endoff, const int* __restrict__ csr,
    const float* __restrict__ inv, const float* __restrict__ t3,
    float* __restrict__ out, int N)
{
    const int i = blockIdx.x * blockDim.x + threadIdx.x;
    if (i >= N) return;
    const int end = endoff[i];
    int p = i ? endoff[i - 1] : 0;
    float s = 0.f;
    for (; p + 4 <= end; p += 4)
        s += (t3[csr[p]] + t3[csr[p + 1]]) + (t3[csr[p + 2]] + t3[csr[p + 3]]);
    for (; p < end; ++p) s += t3[csr[p]];
    out[i] += s * inv[i];
}

extern "C" void kernel_launch(void* const* d_in, const int* in_sizes, int n_in,
                              void* d_out, int out_size, void* d_ws, size_t ws_size,
                              hipStream_t stream) {
    const float* x   = (const float*)d_in[0];
    const int*   ei  = (const int*)d_in[1];
    const float* Wl1 = (const float*)d_in[2];
    const float* bl1 = (const float*)d_in[3];
    const float* Wr1 = (const float*)d_in[4];
    const float* Wl2 = (const float*)d_in[5];
    const float* bl2 = (const float*)d_in[6];
    const float* Wr2 = (const float*)d_in[7];
    const float* Wl3 = (const float*)d_in[8];
    const float* bl3 = (const float*)d_in[9];
    const float* Wr3 = (const float*)d_in[10];
    float* out = (float*)d_out;

    const int N = in_sizes[0] / 256;   // 100000
    const int E = in_sizes[1] / 2;     // 1600000
    const int* src = ei;
    const int* dst = ei + E;

    // ---- workspace layout, race-free aliasing (all bf16 feature bufs) ----
    //   convert_x:  W X1b[0,51.2)
    //   L1 gemm:    R X1b               W T1b[51.2,102.4)  W A1b[102.4,153.6)
    //   agg256_b:   R T1b,A1b           W X2b[0,51.2)      (X1b dead)
    //   L2 gemm:    R X2b               W T2b[51.2,76.8)   W A2b[76.8,102.4)
    //   agg128_b:   R T2b,A2b           W X3b[0,25.6)      (X2b dead)
    //   gemv_l3:    R X3b               W t3,out ; agg1: R t3, RW out
    char* W = (char*)d_ws;
    const size_t MB512 = (size_t)100000 * 512;   // 51.2MB
    unsigned short* X1b = (unsigned short*)(W);
    unsigned short* T1b = (unsigned short*)(W + MB512);
    unsigned short* A1b = (unsigned short*)(W + 2 * MB512);
    unsigned short* X2b = (unsigned short*)(W);
    unsigned short* T2b = (unsigned short*)(W + MB512);
    unsigned short* A2b = (unsigned short*)(W + MB512 + MB512 / 2);
    unsigned short* X3b = (unsigned short*)(W);
    char* S = W + 3 * MB512;                     // smalls @ 153.6M
    float* inv    = (float*)(S);
    int*   endoff = (int*)(S + (size_t)N * 4);
    int*   bsums  = (int*)(S + (size_t)N * 8);
    float* t3     = (float*)(S + (size_t)N * 8 + 1024);
    int*   csr    = (int*)(S + (size_t)N * 12 + 1024);
    unsigned short* Wl1s = (unsigned short*)(S + (size_t)N * 12 + 1024 + (size_t)E * 4);
    unsigned short* Wr1s = Wl1s + 65536;
    unsigned short* Wl2s = Wr1s + 65536;
    unsigned short* Wr2s = Wl2s + 32768;

    // ---- prep: conversions + CSR ----
    convert_x<<<(N * 64 + 255) / 256, 256, 0, stream>>>(x, X1b, N * 64);
    prep_w<<<(65536 + 255) / 256, 256, 0, stream>>>(Wl1, Wl1s, 65536, 8);
    prep_w<<<(65536 + 255) / 256, 256, 0, stream>>>(Wr1, Wr1s, 65536, 8);
    prep_w<<<(32768 + 255) / 256, 256, 0, stream>>>(Wl2, Wl2s, 32768, 7);
    prep_w<<<(32768 + 255) / 256, 256, 0, stream>>>(Wr2, Wr2s, 32768, 7);

    hipMemsetAsync(endoff, 0, (size_t)N * sizeof(int), stream);
    count_deg<<<(E + 255) / 256, 256, 0, stream>>>(dst, endoff, E);
    const int nScanBlocks = (N + 1023) / 1024;
    scan_phaseA<<<nScanBlocks, 256, 0, stream>>>(endoff, bsums, N);
    scan_phaseB<<<1, 256, 0, stream>>>(bsums, nScanBlocks);
    scan_phaseC<<<nScanBlocks, 256, 0, stream>>>(endoff, bsums, N);
    fill_csr<<<(E + 255) / 256, 256, 0, stream>>>(src, dst, endoff, csr, E);
    inv_from_end<<<(N + 255) / 256, 256, 0, stream>>>(endoff, inv, N);

    const int gy = (N + 127) / 128;  // 782 row-blocks

    // Layer 1: T1b = bf16(X@Wl1) ; A1b = bf16(X@Wr1 + bl1)
    gemm_bf16<<<dim3(4, gy), 256, 0, stream>>>(X1b, Wl1s, Wr1s, bl1, T1b, A1b, N, 256);
    agg256_b<<<(N * 64 + 255) / 256, 256, 0, stream>>>(endoff, csr, inv, T1b, A1b, X2b, N);

    // Layer 2 (K=256: h1=256)
    gemm_bf16<<<dim3(2, gy), 256, 0, stream>>>(X2b, Wl2s, Wr2s, bl2, T2b, A2b, N, 128);
    agg128_b<<<(N * 32 + 255) / 256, 256, 0, stream>>>(endoff, csr, inv, T2b, A2b, X3b, N);

    // Layer 3
    gemv_l3<<<(N * 64 + 255) / 256, 256, 0, stream>>>(X3b, Wl3, Wr3, bl3, t3, out, N);
    agg1<<<(N + 255) / 256, 256, 0, stream>>>(endoff, csr, inv, t3, out, N);
}